// Round 1
// baseline (297.604 us; speedup 1.0000x reference)
//
#include <hip/hip_runtime.h>

// FP16 bit-vector -> FP32 bit-vector converter.
// Input:  N x 16 float32, each exactly 0.0 or 1.0 (s, e[5], m[10], MSB-first)
// Output: N x 32 float32 (s, exp[8], mant[23], MSB-first)
//
// Collapsed soft-logic -> integer bit manipulation:
//   e==0,m==0 : exp=0, mant=0
//   e==0,m!=0 : k = leading-zero count within 10-bit m; exp=112-k,
//               mant = (m << (14+k)) & 0x7FFFFF   (leading 1 shifted out)
//   e==31     : exp=255, mant=m<<13  (inf: m=0 -> mant=0; nan: payload kept)
//   else      : exp=e+112, mant=m<<13

__global__ __launch_bounds__(256) void fp16_to_fp32_bits_kernel(
    const uint4* __restrict__ in,   // N*4 uint4 (16 floats/row, bit-tested)
    float4* __restrict__ out,       // N*8 float4 (32 floats/row)
    int n)
{
    int row = blockIdx.x * blockDim.x + threadIdx.x;
    if (row >= n) return;

    const uint4* p = in + (size_t)row * 4;
    uint4 a = p[0];
    uint4 b = p[1];
    uint4 c = p[2];
    uint4 d = p[3];

    unsigned int h = 0;
    h |= (unsigned)(a.x != 0u) << 15;
    h |= (unsigned)(a.y != 0u) << 14;
    h |= (unsigned)(a.z != 0u) << 13;
    h |= (unsigned)(a.w != 0u) << 12;
    h |= (unsigned)(b.x != 0u) << 11;
    h |= (unsigned)(b.y != 0u) << 10;
    h |= (unsigned)(b.z != 0u) << 9;
    h |= (unsigned)(b.w != 0u) << 8;
    h |= (unsigned)(c.x != 0u) << 7;
    h |= (unsigned)(c.y != 0u) << 6;
    h |= (unsigned)(c.z != 0u) << 5;
    h |= (unsigned)(c.w != 0u) << 4;
    h |= (unsigned)(d.x != 0u) << 3;
    h |= (unsigned)(d.y != 0u) << 2;
    h |= (unsigned)(d.z != 0u) << 1;
    h |= (unsigned)(d.w != 0u);

    unsigned int s = h >> 15;
    unsigned int e = (h >> 10) & 31u;
    unsigned int m = h & 1023u;

    unsigned int exp32, mant;
    if (e == 0u) {
        if (m == 0u) {
            exp32 = 0u; mant = 0u;
        } else {
            int k = __clz((int)m) - 22;           // k in [0,9]
            exp32 = 112u - (unsigned)k;
            mant  = (m << (14 + k)) & 0x7FFFFFu;  // leading 1 drops out
        }
    } else if (e == 31u) {
        exp32 = 255u;
        mant  = m << 13;                          // inf: 0; nan: payload<<13
    } else {
        exp32 = e + 112u;
        mant  = m << 13;
    }

    unsigned int r = (s << 31) | (exp32 << 23) | mant;

    float4* q = out + (size_t)row * 8;
#pragma unroll
    for (int j = 0; j < 8; ++j) {
        float4 v;
        v.x = ((r >> (31 - 4 * j)) & 1u) ? 1.0f : 0.0f;
        v.y = ((r >> (30 - 4 * j)) & 1u) ? 1.0f : 0.0f;
        v.z = ((r >> (29 - 4 * j)) & 1u) ? 1.0f : 0.0f;
        v.w = ((r >> (28 - 4 * j)) & 1u) ? 1.0f : 0.0f;
        q[j] = v;
    }
}

extern "C" void kernel_launch(void* const* d_in, const int* in_sizes, int n_in,
                              void* d_out, int out_size, void* d_ws, size_t ws_size,
                              hipStream_t stream) {
    (void)d_ws; (void)ws_size; (void)n_in; (void)out_size;
    int n = in_sizes[0] / 16;   // number of rows
    const uint4* in = (const uint4*)d_in[0];
    float4* out = (float4*)d_out;
    int blocks = (n + 255) / 256;
    fp16_to_fp32_bits_kernel<<<blocks, 256, 0, stream>>>(in, out, n);
}

// Round 2
// 135.622 us; speedup vs baseline: 2.1944x; 2.1944x over previous
//
#include <hip/hip_runtime.h>

// FP16 bit-vector -> FP32 bit-vector converter, wave-cooperative layout.
// Input:  N x 16 float32 (0.0/1.0), MSB-first fp16 bits (s, e[5], m[10])
// Output: N x 32 float32, MSB-first fp32 bits (s, exp[8], mant[23])
//
// Each wave (64 lanes) handles 16 rows:
//   load : lane l reads uint4 #(base_g+l)          -> contiguous 1 KiB/instr
//   bits : 4x __ballot (64-bit) hold all 16 rows' 16-bit patterns
//   store: lane l writes out4[2*base_g+l], [..+64+l] -> contiguous 1 KiB/instr

typedef unsigned long long ull;

__device__ __forceinline__ unsigned h_from_ballots(ull b0, ull b1, ull b2, ull b3,
                                                   int base) {
    // Row occupies lanes base..base+3; lane base+i, component c holds
    // input float f = 4*i + c, which is h bit (15 - f).
    unsigned t0 = (unsigned)(b0 >> base);
    unsigned t1 = (unsigned)(b1 >> base);
    unsigned t2 = (unsigned)(b2 >> base);
    unsigned t3 = (unsigned)(b3 >> base);
    return ((t0 & 1u) << 15) | ((t1 & 1u) << 14) | ((t2 & 1u) << 13) | ((t3 & 1u) << 12) |
           (((t0 >> 1) & 1u) << 11) | (((t1 >> 1) & 1u) << 10) | (((t2 >> 1) & 1u) << 9)  | (((t3 >> 1) & 1u) << 8) |
           (((t0 >> 2) & 1u) << 7)  | (((t1 >> 2) & 1u) << 6)  | (((t2 >> 2) & 1u) << 5)  | (((t3 >> 2) & 1u) << 4) |
           (((t0 >> 3) & 1u) << 3)  | (((t1 >> 3) & 1u) << 2)  | (((t2 >> 3) & 1u) << 1)  | ((t3 >> 3) & 1u);
}

__device__ __forceinline__ unsigned fp16_bits_to_fp32_bits(unsigned h) {
    unsigned s = h >> 15;
    unsigned e = (h >> 10) & 31u;
    unsigned m = h & 1023u;
    int k = (m == 0u) ? 10 : (__clz((int)m) - 22);        // leading zeros in 10-bit m
    unsigned sub_mant = (m << (14 + k)) & 0x7FFFFFu;      // leading 1 shifted out
    unsigned sub_exp  = m ? (112u - (unsigned)k) : 0u;
    unsigned exp32 = (e == 0u) ? sub_exp : ((e == 31u) ? 255u : e + 112u);
    unsigned mant  = (e == 0u) ? sub_mant : (m << 13);    // e==31: inf->0, nan payload
    return (s << 31) | (exp32 << 23) | mant;
}

__device__ __forceinline__ float4 nib_to_f4(unsigned nib) {
    float4 v;
    v.x = (float)((nib >> 3) & 1u);
    v.y = (float)((nib >> 2) & 1u);
    v.z = (float)((nib >> 1) & 1u);
    v.w = (float)(nib & 1u);
    return v;
}

__global__ __launch_bounds__(256) void fp16_to_fp32_bits_kernel(
    const uint4* __restrict__ in,    // 4*N uint4 (16 floats/row, bit-tested)
    float4* __restrict__ out,        // 8*N float4 (32 floats/row)
    unsigned total4,                 // 4*N
    unsigned nrows)                  // N
{
    unsigned g = blockIdx.x * 256u + threadIdx.x;
    int l = threadIdx.x & 63;

    bool valid = g < total4;
    uint4 a = valid ? in[g] : make_uint4(0u, 0u, 0u, 0u);

    ull b0 = __ballot(a.x != 0u);
    ull b1 = __ballot(a.y != 0u);
    ull b2 = __ballot(a.z != 0u);
    ull b3 = __ballot(a.w != 0u);

    unsigned base_g   = g - (unsigned)l;   // wave-aligned uint4 index
    unsigned base_row = base_g >> 2;       // first of this wave's 16 rows

    int rA = l >> 3;                       // 0..7 ; second row is rA+8
    unsigned hA = h_from_ballots(b0, b1, b2, b3, 4 * rA);
    unsigned hB = h_from_ballots(b0, b1, b2, b3, 4 * rA + 32);
    unsigned rsA = fp16_bits_to_fp32_bits(hA);
    unsigned rsB = fp16_bits_to_fp32_bits(hB);

    int j = l & 7;                         // float4 chunk within the row
    unsigned nibA = (rsA >> (28 - 4 * j)) & 0xFu;
    unsigned nibB = (rsB >> (28 - 4 * j)) & 0xFu;

    unsigned outbase = 2u * base_g;        // float4 index of wave's output
    if (base_row + (unsigned)rA < nrows)
        out[outbase + (unsigned)l] = nib_to_f4(nibA);
    if (base_row + 8u + (unsigned)rA < nrows)
        out[outbase + 64u + (unsigned)l] = nib_to_f4(nibB);
}

extern "C" void kernel_launch(void* const* d_in, const int* in_sizes, int n_in,
                              void* d_out, int out_size, void* d_ws, size_t ws_size,
                              hipStream_t stream) {
    (void)d_ws; (void)ws_size; (void)n_in; (void)out_size;
    unsigned n = (unsigned)(in_sizes[0] / 16);  // rows
    unsigned total4 = n * 4u;                   // uint4 elements in input
    const uint4* in = (const uint4*)d_in[0];
    float4* out = (float4*)d_out;
    unsigned blocks = (total4 + 255u) / 256u;
    fp16_to_fp32_bits_kernel<<<blocks, 256, 0, stream>>>(in, out, total4, n);
}